// Round 7
// baseline (1145.084 us; speedup 1.0000x reference)
//
#include <hip/hip_runtime.h>
#include <cstdint>
#include <cstddef>

#define NEG_SLOPE 0.01f

__device__ __forceinline__ float leakyf(float v) { return v > 0.f ? v : NEG_SLOPE * v; }

// ---------------- weight transpose: w[co][ci][k][k] -> wT[ci][k][k][co] ----------------
__global__ void wtrans_k(const float* __restrict__ w, float* __restrict__ wT,
                         int CIN, int COUT, int KK) {
    int idx = blockIdx.x * blockDim.x + threadIdx.x;
    int total = COUT * CIN * KK;
    if (idx >= total) return;
    int co = idx / (CIN * KK);
    int rem = idx % (CIN * KK);
    wT[(size_t)rem * COUT + co] = w[idx];
}

// ---------------- pad input images into zero-bordered buffer [2][3][H+8][W+8] ----------------
__global__ void pad_in_k(const float* __restrict__ x1, const float* __restrict__ x2,
                         float* __restrict__ dst, int C, int H, int W) {
    int idx = blockIdx.x * blockDim.x + threadIdx.x;  // exact grid: 2*C*H*W
    int HW = H * W;
    int img = idx / (C * HW);
    int rem = idx % (C * HW);
    int c = rem / HW;
    int p = rem % HW;
    int y = p / W, x = p % W;
    int Wp = W + 8, Hp = H + 8;
    dst[(((size_t)img * C + c) * Hp + y + 4) * Wp + x + 4] = (img ? x2 : x1)[rem];
}

// ---------------- encoder conv on padded input, 1x4 register tile, TOUT=4 cout ----------------
template <int CIN, int COUT, int K, int NSPLIT>
__global__ __launch_bounds__(256) void conv_enc_tile_k(
        const float* __restrict__ inpad, const float* __restrict__ wT,
        const float* __restrict__ bias,
        float* __restrict__ out1, float* __restrict__ out2,
        float* __restrict__ partial, int H, int W) {
    const int P = K / 2;
    const int Wp = W + 8, Hp = H + 8;
    const int NCOG = COUT / 4;
    const int CSP = CIN / NSPLIT;
    int cog = blockIdx.y % NCOG;
    int s = blockIdx.y / NCOG;
    int img = blockIdx.z;
    int tile = blockIdx.x * 256 + threadIdx.x;
    int wt = W >> 2;
    int tx = tile % wt, ty = tile / wt;
    int x0 = tx << 2;
    int og = cog * 4;
    int ci0 = s * CSP;

    float acc[4][4];
#pragma unroll
    for (int t = 0; t < 4; ++t) {
        float b = (NSPLIT == 1) ? bias[og + t] : 0.f;
#pragma unroll
        for (int p = 0; p < 4; ++p) acc[t][p] = b;
    }

    const float* ibase = inpad + ((size_t)img * CIN + ci0) * Hp * Wp;
#pragma unroll
    for (int ci = 0; ci < CSP; ++ci) {
        const float* ip = ibase + (size_t)ci * Hp * Wp;
#pragma unroll
        for (int ky = 0; ky < K; ++ky) {
            const float* rp = ip + (size_t)(ty + 4 - P + ky) * Wp + x0;  // 16B aligned
            float4 a0 = *(const float4*)(rp);
            float4 a1 = *(const float4*)(rp + 4);
            float4 a2 = *(const float4*)(rp + 8);
            float win[12] = {a0.x, a0.y, a0.z, a0.w, a1.x, a1.y, a1.z, a1.w,
                             a2.x, a2.y, a2.z, a2.w};
            const float* wrow = wT + (size_t)(((ci0 + ci) * K + ky) * K) * COUT + og;
#pragma unroll
            for (int kx = 0; kx < K; ++kx) {
                float4 wv = *(const float4*)(wrow + (size_t)kx * COUT);
#pragma unroll
                for (int p = 0; p < 4; ++p) {
                    float v = win[4 - P + kx + p];
                    acc[0][p] += v * wv.x;
                    acc[1][p] += v * wv.y;
                    acc[2][p] += v * wv.z;
                    acc[3][p] += v * wv.w;
                }
            }
        }
    }

    size_t pixbase = (size_t)ty * W + x0;
    if (NSPLIT == 1) {
        float* out = img ? out2 : out1;
#pragma unroll
        for (int t = 0; t < 4; ++t) {
            float4 r;
            r.x = leakyf(acc[t][0]); r.y = leakyf(acc[t][1]);
            r.z = leakyf(acc[t][2]); r.w = leakyf(acc[t][3]);
            *(float4*)(out + (size_t)(og + t) * H * W + pixbase) = r;
        }
    } else {
        float* pp = partial + (((size_t)s * 2 + img) * COUT + og) * H * W + pixbase;
#pragma unroll
        for (int t = 0; t < 4; ++t) {
            float4 r;
            r.x = acc[t][0]; r.y = acc[t][1]; r.z = acc[t][2]; r.w = acc[t][3];
            *(float4*)(pp + (size_t)t * H * W) = r;
        }
    }
}

// ---------------- reduce partials + bias + leaky (float4) ----------------
template <int NSPLIT>
__global__ __launch_bounds__(256) void reduce4_k(const float4* __restrict__ partial,
                                                 const float* __restrict__ bias,
                                                 float* __restrict__ out1,
                                                 float* __restrict__ out2,
                                                 int COUT, int HW) {
    int idx = blockIdx.x * 256 + threadIdx.x;  // exact grid: 2*COUT*HW/4
    int hq = HW >> 2;
    int cq = COUT * hq;
    int img = idx / cq;
    int rem = idx % cq;
    int co = rem / hq;
    float b = bias[co];
    float4 sum; sum.x = b; sum.y = b; sum.z = b; sum.w = b;
#pragma unroll
    for (int sp = 0; sp < NSPLIT; ++sp) {
        float4 v = partial[(size_t)(sp * 2 + img) * cq + rem];
        sum.x += v.x; sum.y += v.y; sum.z += v.z; sum.w += v.w;
    }
    float4 r;
    r.x = leakyf(sum.x); r.y = leakyf(sum.y); r.z = leakyf(sum.z); r.w = leakyf(sum.w);
    ((float4*)(img ? out2 : out1))[rem] = r;
}

// ---------------- 2x2 maxpool, writes into padded next-level buffer ----------------
__global__ void maxpool_pad_k(const float* __restrict__ in, float* __restrict__ outp,
                              int C, int H, int W) {
    int H2 = H >> 1, W2 = W >> 1;
    int idx = blockIdx.x * blockDim.x + threadIdx.x;  // exact grid: C*H2*W2
    int x = idx % W2;
    int y = (idx / W2) % H2;
    int c = idx / (W2 * H2);
    const float* p = in + ((size_t)c * H + 2 * y) * W + 2 * x;
    float v = fmaxf(fmaxf(p[0], p[1]), fmaxf(p[W], p[W + 1]));
    outp[((size_t)c * (H2 + 8) + y + 4) * (W2 + 8) + x + 4] = v;
}

// ---------------- gather Q = h1[:, pts] ----------------
__global__ void gatherQ_k(const float* __restrict__ h1, const int* __restrict__ pts,
                          float* __restrict__ Q, int C, int Wdim, int shift) {
    int idx = blockIdx.x * blockDim.x + threadIdx.x;
    if (idx >= C * 256) return;
    int l = idx & 255;
    int c = idx >> 8;
    int r = pts[2 * l] >> shift;
    int cc = pts[2 * l + 1] >> shift;
    Q[idx] = h1[(size_t)c * Wdim * Wdim + (size_t)r * Wdim + cc];
}

// ---------------- S[m*256+l] = sum_c h2[c][m]*Q[c][l]  (flat (h,w,l) order) ----------------
__global__ void attn_scores_k(const float* __restrict__ h2, const float* __restrict__ Q,
                              float* __restrict__ S, int C, int HW) {
    int m = blockIdx.x;   // pixel
    int l = threadIdx.x;  // 256 points
    float acc = 0.f;
    for (int c = 0; c < C; ++c) acc += h2[(size_t)c * HW + m] * Q[c * 256 + l];
    S[(size_t)m * 256 + l] = acc;
}

// ---------------- softmax over contiguous chunks of size HW, float4 ----------------
template <int THREADS>
__global__ void softmax_chunk_v4_k(float* __restrict__ S, int HW) {
    float* p = S + (size_t)blockIdx.x * HW;
    float4* p4 = (float4*)p;
    int t = threadIdx.x;
    int n4 = HW >> 2;
    float m = -3.4e38f, s = 0.f;
    for (int i = t; i < n4; i += THREADS) {
        float4 v = p4[i];
        float mn = fmaxf(fmaxf(m, v.x), fmaxf(fmaxf(v.y, v.z), v.w));
        s = s * __expf(m - mn) + __expf(v.x - mn) + __expf(v.y - mn) +
            __expf(v.z - mn) + __expf(v.w - mn);
        m = mn;
    }
    __shared__ float sm[THREADS], ss[THREADS];
    sm[t] = m; ss[t] = s;
    __syncthreads();
    for (int o = THREADS >> 1; o > 0; o >>= 1) {
        if (t < o) {
            float m2 = fmaxf(sm[t], sm[t + o]);
            ss[t] = ss[t] * __expf(sm[t] - m2) + ss[t + o] * __expf(sm[t + o] - m2);
            sm[t] = m2;
        }
        __syncthreads();
    }
    float M = sm[0], inv = 1.f / ss[0];
    for (int i = t; i < n4; i += THREADS) {
        float4 v = p4[i];
        v.x = __expf(v.x - M) * inv;
        v.y = __expf(v.y - M) * inv;
        v.z = __expf(v.z - M) * inv;
        v.w = __expf(v.w - M) * inv;
        p4[i] = v;
    }
}

// ---------------- transposed conv k3 s2 p1 op1, batch 1, +bias (padded input 24x24) ----------------
__global__ void convT_b1_k(const float* __restrict__ in, const float* __restrict__ w,
                           const float* __restrict__ bias, float* __restrict__ out,
                           int Cin, int Cout, int H, int W) {
    int H2 = 2 * H, W2 = 2 * W;
    int idx = blockIdx.x * blockDim.x + threadIdx.x;
    int total = Cout * H2 * W2;
    if (idx >= total) return;
    int x = idx % W2;
    int y = (idx / W2) % H2;
    int o = idx / (W2 * H2);
    int kys[2], iys[2], nky, kxs[2], ixs[2], nkx;
    if (y & 1) {
        nky = 0;
        int iy0 = (y + 1) >> 1;
        if (iy0 < H) { kys[nky] = 0; iys[nky] = iy0; ++nky; }
        kys[nky] = 2; iys[nky] = (y - 1) >> 1; ++nky;
    } else { kys[0] = 1; iys[0] = y >> 1; nky = 1; }
    if (x & 1) {
        nkx = 0;
        int ix0 = (x + 1) >> 1;
        if (ix0 < W) { kxs[nkx] = 0; ixs[nkx] = ix0; ++nkx; }
        kxs[nkx] = 2; ixs[nkx] = (x - 1) >> 1; ++nkx;
    } else { kxs[0] = 1; ixs[0] = x >> 1; nkx = 1; }
    const int Wp = 24;
    float acc = bias[o];
    for (int ci = 0; ci < Cin; ++ci) {
        const float* ip = in + (size_t)ci * Wp * Wp;
        const float* wp = w + ((size_t)ci * Cout + o) * 9;
        for (int a = 0; a < nky; ++a)
            for (int b = 0; b < nkx; ++b)
                acc += ip[(size_t)(iys[a] + 4) * Wp + ixs[b] + 4] * wp[kys[a] * 3 + kxs[b]];
    }
    out[idx] = acc;
}

// ---------------- broadcast (1,C,H,W)*(256,1,H,W) + leaky ----------------
__global__ void bcast_mul_leaky_k(const float* __restrict__ t, const float* __restrict__ attn,
                                  float* __restrict__ out, int C, int HW) {
    size_t idx = (size_t)blockIdx.x * blockDim.x + threadIdx.x;
    size_t total = (size_t)256 * C * HW;
    if (idx >= total) return;
    int p = (int)(idx % HW);
    int c = (int)((idx / HW) % C);
    int n = (int)(idx / ((size_t)HW * C));
    out[idx] = leakyf(t[(size_t)c * HW + p] * attn[(size_t)n * HW + p]);
}

// ---------------- row-parity fused convT (batch 256) * attn (+leaky) ----------------
// Output row Y = 2r (ODD=false) or 2r+1 (ODD=true), r in [0,HH).
// One thread = 8 contiguous outputs of one row for COG output channels.
//   even: out(2r,2ix)=w4*a[ix]; out(2r,2ix+1)=w3*a[ix+1]+w5*a[ix]        (row a = r)
//   odd : out(2r+1,2ix)=w1*b[ix]+w7*a[ix];
//         out(2r+1,2ix+1)=w0*b[ix+1]+w2*b[ix]+w6*a[ix+1]+w8*a[ix]       (row b = r+1, zero if r+1==HH)
template <int CIN, int COUT, int COG, int HH, int WW, bool ODD, bool LEAKY, bool VALIDMAX>
__global__ __launch_bounds__(256) void convT_rows_k(
        const float* __restrict__ in, const float* __restrict__ w,
        const float* __restrict__ bias, const float* __restrict__ attn,
        float* __restrict__ out, int* __restrict__ validFlag) {
    const int TPR = WW / 4;           // threads per row
    const int NCG = COUT / COG;
    int idx = blockIdx.x * 256 + threadIdx.x;   // exact grid
    int t = idx % TPR;
    int rest = idx / TPR;
    int r = rest % HH;
    rest /= HH;
    int cg = rest % NCG;
    int n = rest / NCG;
    int ix0 = t << 2;
    bool okx = (ix0 + 4 < WW);
    bool okb = (r + 1 < HH);

    float acc[COG][8];
#pragma unroll
    for (int c = 0; c < COG; ++c)
#pragma unroll
        for (int q = 0; q < 8; ++q) acc[c][q] = 0.f;

    const float* pa = in + ((size_t)n * CIN * HH + r) * WW + ix0;
#pragma unroll
    for (int ci = 0; ci < CIN; ++ci) {
        float4 a = *(const float4*)pa;
        float a4 = __shfl_down(a.x, 1, 64);
        if (!okx) a4 = 0.f;
        float av[5] = {a.x, a.y, a.z, a.w, a4};
        float bv[5];
        if (ODD) {
            const float* pb = pa + (okb ? WW : 0);
            float4 b = *(const float4*)pb;
            float b4 = __shfl_down(b.x, 1, 64);
            bv[0] = okb ? b.x : 0.f;
            bv[1] = okb ? b.y : 0.f;
            bv[2] = okb ? b.z : 0.f;
            bv[3] = okb ? b.w : 0.f;
            bv[4] = (okb && okx) ? b4 : 0.f;
        }
        const float* wc = w + (size_t)ci * COUT * 9 + (size_t)cg * COG * 9;
#pragma unroll
        for (int c = 0; c < COG; ++c) {
            const float* qw = wc + c * 9;
            if (!ODD) {
                float w3 = qw[3], w4 = qw[4], w5 = qw[5];
#pragma unroll
                for (int q = 0; q < 4; ++q) {
                    acc[c][2 * q] += w4 * av[q];
                    acc[c][2 * q + 1] += w3 * av[q + 1] + w5 * av[q];
                }
            } else {
                float w0 = qw[0], w1 = qw[1], w2 = qw[2];
                float w6 = qw[6], w7 = qw[7], w8 = qw[8];
#pragma unroll
                for (int q = 0; q < 4; ++q) {
                    acc[c][2 * q] += w1 * bv[q] + w7 * av[q];
                    acc[c][2 * q + 1] += w0 * bv[q + 1] + w2 * bv[q] + w6 * av[q + 1] + w8 * av[q];
                }
            }
        }
        pa += HH * WW;
    }

    const int H2 = 2 * HH, W2 = 2 * WW;
    int Y = 2 * r + (ODD ? 1 : 0);
    const float* ap = attn + ((size_t)n * H2 + Y) * W2 + 2 * ix0;
    float4 at0 = *(const float4*)ap;
    float4 at1 = *(const float4*)(ap + 4);
    float atv[8] = {at0.x, at0.y, at0.z, at0.w, at1.x, at1.y, at1.z, at1.w};

    float vmax = -3.4e38f;
#pragma unroll
    for (int c = 0; c < COG; ++c) {
        int o = cg * COG + c;
        float bs = bias[o];
        float res[8];
#pragma unroll
        for (int q = 0; q < 8; ++q) {
            float v = (acc[c][q] + bs) * atv[q];
            if (LEAKY) v = leakyf(v);
            res[q] = v;
            if (VALIDMAX) vmax = fmaxf(vmax, v);
        }
        float* ob = out + (((size_t)n * COUT + o) * H2 + Y) * W2 + 2 * ix0;
        float4 s0; s0.x = res[0]; s0.y = res[1]; s0.z = res[2]; s0.w = res[3];
        float4 s1; s1.x = res[4]; s1.y = res[5]; s1.z = res[6]; s1.w = res[7];
        *(float4*)ob = s0;
        *(float4*)(ob + 4) = s1;
    }

    if (VALIDMAX) {
        __shared__ float smax[256];
        int tt = threadIdx.x;
        smax[tt] = vmax;
        __syncthreads();
        for (int o = 128; o > 0; o >>= 1) {
            if (tt < o) smax[tt] = fmaxf(smax[tt], smax[tt + o]);
            __syncthreads();
        }
        if (tt == 0 && smax[0] > 1.f) atomicOr(&validFlag[n], 1);
    }
}

// ---------------- decode valid flags ----------------
__global__ void valid_decode_k(const int* __restrict__ flags, float* __restrict__ vout) {
    int l = threadIdx.x;
    vout[l] = flags[l] ? 1.f : 0.f;
}

extern "C" void kernel_launch(void* const* d_in, const int* in_sizes, int n_in,
                              void* d_out, int out_size, void* d_ws, size_t ws_size,
                              hipStream_t stream) {
    const float* x1 = (const float*)d_in[0];
    const float* x2 = (const float*)d_in[1];
    const int* pts = (const int*)d_in[2];
    const float* ew[4] = {(const float*)d_in[3], (const float*)d_in[5], (const float*)d_in[7], (const float*)d_in[9]};
    const float* eb[4] = {(const float*)d_in[4], (const float*)d_in[6], (const float*)d_in[8], (const float*)d_in[10]};
    const float* dw[4] = {(const float*)d_in[11], (const float*)d_in[13], (const float*)d_in[15], (const float*)d_in[17]};
    const float* db[4] = {(const float*)d_in[12], (const float*)d_in[14], (const float*)d_in[16], (const float*)d_in[18]};

    float* ws = (float*)d_ws;
    float* h1a = ws;                    // 524288
    float* h2a = h1a + 524288;          // 524288
    float* Q   = h2a + 524288;          // 16384
    float* t0  = Q + 16384;             // 32768
    float* attn3 = t0 + 32768;          // 262144   (32x32 * 256)
    float* attn2 = attn3 + 262144;      // 1048576  (64x64 * 256)
    float* attn1 = attn2 + 1048576;     // 4194304  (128x128 * 256)
    float* attn0 = attn1 + 4194304;     // 16777216 (256x256 * 256)
    float* bufD1 = attn0 + 16777216;    // 33554432
    float* wT0 = bufD1 + 33554432;      // 216
    float* wT1 = wT0 + 216;             // 3200
    float* wT2 = wT1 + 3200;            // 25088
    float* wT3 = wT2 + 25088;           // 165888
    float* partialBuf = wT3 + 165888;   // 2097152
    int* validFlag = (int*)(partialBuf + 2097152);  // 256 ints
    // pad buffers alias bufD1 (dead until decoder; convT_b1 reads pad4 before bufD1 written)
    float* pad0 = bufD1;                // 2*3*264*264  = 418176
    float* pad1 = pad0 + 418176;        // 2*8*136*136  = 295936
    float* pad2 = pad1 + 295936;        // 2*16*72*72   = 165888
    float* pad3 = pad2 + 165888;        // 2*32*40*40   = 102400
    float* pad4 = pad3 + 102400;        // 2*64*24*24   = 73728   (total 1056128)
    float* attnArr[4] = {attn0, attn1, attn2, attn3};

    float* conf = (float*)d_out;            // 16777216
    float* validOut = conf + 16777216;      // 256

    // zero pad borders (whole pad region) + valid flags each call
    hipMemsetAsync(pad0, 0, (size_t)1056128 * 4, stream);
    hipMemsetAsync(validFlag, 0, 256 * 4, stream);

    // weight pre-transpose (tiny)
    wtrans_k<<<(216 + 255) / 256, 256, 0, stream>>>(ew[0], wT0, 3, 8, 9);
    wtrans_k<<<(3200 + 255) / 256, 256, 0, stream>>>(ew[1], wT1, 8, 16, 25);
    wtrans_k<<<(25088 + 255) / 256, 256, 0, stream>>>(ew[2], wT2, 16, 32, 49);
    wtrans_k<<<(165888 + 255) / 256, 256, 0, stream>>>(ew[3], wT3, 32, 64, 81);

    // stage level-0 inputs into padded layout
    pad_in_k<<<(2 * 3 * 65536) / 256, 256, 0, stream>>>(x1, x2, pad0, 3, 256, 256);

    const int Hs[4] = {256, 128, 64, 32};
    const int Couts[4] = {8, 16, 32, 64};
    float* padIn[4] = {pad0, pad1, pad2, pad3};
    float* padOut[4] = {pad1, pad2, pad3, pad4};
    const int padOutImgStride[4] = {8 * 136 * 136, 16 * 72 * 72, 32 * 40 * 40, 64 * 24 * 24};

    for (int lv = 0; lv < 4; ++lv) {
        int Hc = Hs[lv], HW = Hc * Hc;
        if (lv == 0) {
            dim3 grid(HW / 4 / 256, 2 * 1, 2);
            conv_enc_tile_k<3, 8, 3, 1><<<grid, 256, 0, stream>>>(
                padIn[0], wT0, eb[0], h1a, h2a, partialBuf, Hc, Hc);
        } else if (lv == 1) {
            dim3 grid(HW / 4 / 256, 4 * 4, 2);
            conv_enc_tile_k<8, 16, 5, 4><<<grid, 256, 0, stream>>>(
                padIn[1], wT1, eb[1], h1a, h2a, partialBuf, Hc, Hc);
            reduce4_k<4><<<(2 * 16 * HW / 4) / 256, 256, 0, stream>>>(
                (const float4*)partialBuf, eb[1], h1a, h2a, 16, HW);
        } else if (lv == 2) {
            dim3 grid(HW / 4 / 256, 8 * 8, 2);
            conv_enc_tile_k<16, 32, 7, 8><<<grid, 256, 0, stream>>>(
                padIn[2], wT2, eb[2], h1a, h2a, partialBuf, Hc, Hc);
            reduce4_k<8><<<(2 * 32 * HW / 4) / 256, 256, 0, stream>>>(
                (const float4*)partialBuf, eb[2], h1a, h2a, 32, HW);
        } else {
            dim3 grid(HW / 4 / 256, 16 * 16, 2);
            conv_enc_tile_k<32, 64, 9, 16><<<grid, 256, 0, stream>>>(
                padIn[3], wT3, eb[3], h1a, h2a, partialBuf, Hc, Hc);
            reduce4_k<16><<<(2 * 64 * HW / 4) / 256, 256, 0, stream>>>(
                (const float4*)partialBuf, eb[3], h1a, h2a, 64, HW);
        }
        gatherQ_k<<<(Couts[lv] * 256 + 255) / 256, 256, 0, stream>>>(h1a, pts, Q, Couts[lv], Hc, lv);
        attn_scores_k<<<HW, 256, 0, stream>>>(h2a, Q, attnArr[lv], Couts[lv], HW);
        if (lv < 3)
            softmax_chunk_v4_k<1024><<<256, 1024, 0, stream>>>(attnArr[lv], HW);
        else
            softmax_chunk_v4_k<256><<<256, 256, 0, stream>>>(attnArr[lv], HW);
        int npool = Couts[lv] * (HW / 4);
        maxpool_pad_k<<<npool / 256, 256, 0, stream>>>(h1a, padOut[lv], Couts[lv], Hc, Hc);
        maxpool_pad_k<<<npool / 256, 256, 0, stream>>>(h2a, padOut[lv] + padOutImgStride[lv],
                                                       Couts[lv], Hc, Hc);
    }
    // pad4 img1 section now holds padded encoder output of image 2 (64,16,16)

    // decoder layer 0: convT once at batch 1, then broadcast*attn3 + leaky -> bufD1 (256,32,32,32)
    convT_b1_k<<<(32 * 32 * 32 + 255) / 256, 256, 0, stream>>>(
        pad4 + padOutImgStride[3], dw[0], db[0], t0, 64, 32, 16, 16);
    {
        size_t tot = (size_t)256 * 32 * 1024;
        bcast_mul_leaky_k<<<(unsigned)((tot + 255) / 256), 256, 0, stream>>>(t0, attn3, bufD1, 32, 1024);
    }
    // layer 1: (256,32,32,32) -> (256,16,64,64) * attn2, leaky -> conf (staging)
    // grid per parity: 256n * 32r * 8tpr * 4cg = 262144 threads = 1024 blocks
    convT_rows_k<32, 16, 4, 32, 32, false, true, false><<<1024, 256, 0, stream>>>(
        bufD1, dw[1], db[1], attn2, conf, validFlag);
    convT_rows_k<32, 16, 4, 32, 32, true, true, false><<<1024, 256, 0, stream>>>(
        bufD1, dw[1], db[1], attn2, conf, validFlag);
    // layer 2: (256,16,64,64) -> (256,8,128,128) * attn1, leaky -> bufD1
    // grid per parity: 256n * 64r * 16tpr * 2cg = 524288 threads = 2048 blocks
    convT_rows_k<16, 8, 4, 64, 64, false, true, false><<<2048, 256, 0, stream>>>(
        conf, dw[2], db[2], attn1, bufD1, validFlag);
    convT_rows_k<16, 8, 4, 64, 64, true, true, false><<<2048, 256, 0, stream>>>(
        conf, dw[2], db[2], attn1, bufD1, validFlag);
    // layer 3: (256,8,128,128) -> (256,1,256,256) * attn0, no leaky -> conf, fused valid
    // grid per parity: 256n * 128r * 32tpr = 1048576 threads = 4096 blocks
    convT_rows_k<8, 1, 1, 128, 128, false, false, true><<<4096, 256, 0, stream>>>(
        bufD1, dw[3], db[3], attn0, conf, validFlag);
    convT_rows_k<8, 1, 1, 128, 128, true, false, true><<<4096, 256, 0, stream>>>(
        bufD1, dw[3], db[3], attn0, conf, validFlag);

    valid_decode_k<<<1, 256, 0, stream>>>(validFlag, validOut);
}

// Round 8
// 624.165 us; speedup vs baseline: 1.8346x; 1.8346x over previous
//
#include <hip/hip_runtime.h>
#include <cstdint>
#include <cstddef>

#define NEG_SLOPE 0.01f

__device__ __forceinline__ float leakyf(float v) { return v > 0.f ? v : NEG_SLOPE * v; }

// ---------------- weight transpose: w[co][ci][k][k] -> wT[ci][k][k][co] ----------------
__global__ void wtrans_k(const float* __restrict__ w, float* __restrict__ wT,
                         int CIN, int COUT, int KK) {
    int idx = blockIdx.x * blockDim.x + threadIdx.x;
    int total = COUT * CIN * KK;
    if (idx >= total) return;
    int co = idx / (CIN * KK);
    int rem = idx % (CIN * KK);
    wT[(size_t)rem * COUT + co] = w[idx];
}

// ---------------- pad input images into zero-bordered buffer [2][3][H+8][W+8] ----------------
__global__ void pad_in_k(const float* __restrict__ x1, const float* __restrict__ x2,
                         float* __restrict__ dst, int C, int H, int W) {
    int idx = blockIdx.x * blockDim.x + threadIdx.x;  // exact grid: 2*C*H*W
    int HW = H * W;
    int img = idx / (C * HW);
    int rem = idx % (C * HW);
    int c = rem / HW;
    int p = rem % HW;
    int y = p / W, x = p % W;
    int Wp = W + 8, Hp = H + 8;
    dst[(((size_t)img * C + c) * Hp + y + 4) * Wp + x + 4] = (img ? x2 : x1)[rem];
}

// ---------------- encoder conv on padded input, 1x4 register tile, TOUT=4 cout ----------------
// inpad: [2][CIN][H+8][W+8]; wT: [CIN][K][K][COUT]
// grid: (HW/4/256, (COUT/4)*NSPLIT, 2) -- all exact, no guards
template <int CIN, int COUT, int K, int NSPLIT>
__global__ __launch_bounds__(256) void conv_enc_tile_k(
        const float* __restrict__ inpad, const float* __restrict__ wT,
        const float* __restrict__ bias,
        float* __restrict__ out1, float* __restrict__ out2,
        float* __restrict__ partial, int H, int W) {
    const int P = K / 2;
    const int Wp = W + 8, Hp = H + 8;
    const int NCOG = COUT / 4;
    const int CSP = CIN / NSPLIT;
    int cog = blockIdx.y % NCOG;
    int s = blockIdx.y / NCOG;
    int img = blockIdx.z;
    int tile = blockIdx.x * 256 + threadIdx.x;
    int wt = W >> 2;
    int tx = tile % wt, ty = tile / wt;
    int x0 = tx << 2;
    int og = cog * 4;
    int ci0 = s * CSP;

    float acc[4][4];
#pragma unroll
    for (int t = 0; t < 4; ++t) {
        float b = (NSPLIT == 1) ? bias[og + t] : 0.f;
#pragma unroll
        for (int p = 0; p < 4; ++p) acc[t][p] = b;
    }

    const float* ibase = inpad + ((size_t)img * CIN + ci0) * Hp * Wp;
#pragma unroll
    for (int ci = 0; ci < CSP; ++ci) {
        const float* ip = ibase + (size_t)ci * Hp * Wp;
#pragma unroll
        for (int ky = 0; ky < K; ++ky) {
            const float* rp = ip + (size_t)(ty + 4 - P + ky) * Wp + x0;  // 16B aligned
            float4 a0 = *(const float4*)(rp);
            float4 a1 = *(const float4*)(rp + 4);
            float4 a2 = *(const float4*)(rp + 8);
            float win[12] = {a0.x, a0.y, a0.z, a0.w, a1.x, a1.y, a1.z, a1.w,
                             a2.x, a2.y, a2.z, a2.w};
            const float* wrow = wT + (size_t)(((ci0 + ci) * K + ky) * K) * COUT + og;
#pragma unroll
            for (int kx = 0; kx < K; ++kx) {
                float4 wv = *(const float4*)(wrow + (size_t)kx * COUT);
#pragma unroll
                for (int p = 0; p < 4; ++p) {
                    float v = win[4 - P + kx + p];
                    acc[0][p] += v * wv.x;
                    acc[1][p] += v * wv.y;
                    acc[2][p] += v * wv.z;
                    acc[3][p] += v * wv.w;
                }
            }
        }
    }

    size_t pixbase = (size_t)ty * W + x0;
    if (NSPLIT == 1) {
        float* out = img ? out2 : out1;
#pragma unroll
        for (int t = 0; t < 4; ++t) {
            float4 r;
            r.x = leakyf(acc[t][0]); r.y = leakyf(acc[t][1]);
            r.z = leakyf(acc[t][2]); r.w = leakyf(acc[t][3]);
            *(float4*)(out + (size_t)(og + t) * H * W + pixbase) = r;
        }
    } else {
        float* pp = partial + (((size_t)s * 2 + img) * COUT + og) * H * W + pixbase;
#pragma unroll
        for (int t = 0; t < 4; ++t) {
            float4 r;
            r.x = acc[t][0]; r.y = acc[t][1]; r.z = acc[t][2]; r.w = acc[t][3];
            *(float4*)(pp + (size_t)t * H * W) = r;
        }
    }
}

// ---------------- reduce partials + bias + leaky (float4) ----------------
template <int NSPLIT>
__global__ __launch_bounds__(256) void reduce4_k(const float4* __restrict__ partial,
                                                 const float* __restrict__ bias,
                                                 float* __restrict__ out1,
                                                 float* __restrict__ out2,
                                                 int COUT, int HW) {
    int idx = blockIdx.x * 256 + threadIdx.x;  // exact grid: 2*COUT*HW/4
    int hq = HW >> 2;
    int cq = COUT * hq;
    int img = idx / cq;
    int rem = idx % cq;
    int co = rem / hq;
    float b = bias[co];
    float4 sum; sum.x = b; sum.y = b; sum.z = b; sum.w = b;
#pragma unroll
    for (int sp = 0; sp < NSPLIT; ++sp) {
        float4 v = partial[(size_t)(sp * 2 + img) * cq + rem];
        sum.x += v.x; sum.y += v.y; sum.z += v.z; sum.w += v.w;
    }
    float4 r;
    r.x = leakyf(sum.x); r.y = leakyf(sum.y); r.z = leakyf(sum.z); r.w = leakyf(sum.w);
    ((float4*)(img ? out2 : out1))[rem] = r;
}

// ---------------- 2x2 maxpool, writes into padded next-level buffer ----------------
__global__ void maxpool_pad_k(const float* __restrict__ in, float* __restrict__ outp,
                              int C, int H, int W) {
    int H2 = H >> 1, W2 = W >> 1;
    int idx = blockIdx.x * blockDim.x + threadIdx.x;  // exact grid: C*H2*W2
    int x = idx % W2;
    int y = (idx / W2) % H2;
    int c = idx / (W2 * H2);
    const float* p = in + ((size_t)c * H + 2 * y) * W + 2 * x;
    float v = fmaxf(fmaxf(p[0], p[1]), fmaxf(p[W], p[W + 1]));
    outp[((size_t)c * (H2 + 8) + y + 4) * (W2 + 8) + x + 4] = v;
}

// ---------------- gather Q = h1[:, pts] ----------------
__global__ void gatherQ_k(const float* __restrict__ h1, const int* __restrict__ pts,
                          float* __restrict__ Q, int C, int Wdim, int shift) {
    int idx = blockIdx.x * blockDim.x + threadIdx.x;
    if (idx >= C * 256) return;
    int l = idx & 255;
    int c = idx >> 8;
    int r = pts[2 * l] >> shift;
    int cc = pts[2 * l + 1] >> shift;
    Q[idx] = h1[(size_t)c * Wdim * Wdim + (size_t)r * Wdim + cc];
}

// ---------------- S[m*256+l] = sum_c h2[c][m]*Q[c][l]  (flat (h,w,l) order) ----------------
__global__ void attn_scores_k(const float* __restrict__ h2, const float* __restrict__ Q,
                              float* __restrict__ S, int C, int HW) {
    int m = blockIdx.x;   // pixel
    int l = threadIdx.x;  // 256 points
    float acc = 0.f;
    for (int c = 0; c < C; ++c) acc += h2[(size_t)c * HW + m] * Q[c * 256 + l];
    S[(size_t)m * 256 + l] = acc;
}

// ---------------- softmax over contiguous chunks of size HW, float4 ----------------
template <int THREADS>
__global__ void softmax_chunk_v4_k(float* __restrict__ S, int HW) {
    float* p = S + (size_t)blockIdx.x * HW;
    float4* p4 = (float4*)p;
    int t = threadIdx.x;
    int n4 = HW >> 2;
    float m = -3.4e38f, s = 0.f;
    for (int i = t; i < n4; i += THREADS) {
        float4 v = p4[i];
        float mn = fmaxf(fmaxf(m, v.x), fmaxf(fmaxf(v.y, v.z), v.w));
        s = s * __expf(m - mn) + __expf(v.x - mn) + __expf(v.y - mn) +
            __expf(v.z - mn) + __expf(v.w - mn);
        m = mn;
    }
    __shared__ float sm[THREADS], ss[THREADS];
    sm[t] = m; ss[t] = s;
    __syncthreads();
    for (int o = THREADS >> 1; o > 0; o >>= 1) {
        if (t < o) {
            float m2 = fmaxf(sm[t], sm[t + o]);
            ss[t] = ss[t] * __expf(sm[t] - m2) + ss[t + o] * __expf(sm[t + o] - m2);
            sm[t] = m2;
        }
        __syncthreads();
    }
    float M = sm[0], inv = 1.f / ss[0];
    for (int i = t; i < n4; i += THREADS) {
        float4 v = p4[i];
        v.x = __expf(v.x - M) * inv;
        v.y = __expf(v.y - M) * inv;
        v.z = __expf(v.z - M) * inv;
        v.w = __expf(v.w - M) * inv;
        p4[i] = v;
    }
}

// ---------------- transposed conv k3 s2 p1 op1, batch 1, +bias (padded input 24x24) ----------------
__global__ void convT_b1_k(const float* __restrict__ in, const float* __restrict__ w,
                           const float* __restrict__ bias, float* __restrict__ out,
                           int Cin, int Cout, int H, int W) {
    int H2 = 2 * H, W2 = 2 * W;
    int idx = blockIdx.x * blockDim.x + threadIdx.x;
    int total = Cout * H2 * W2;
    if (idx >= total) return;
    int x = idx % W2;
    int y = (idx / W2) % H2;
    int o = idx / (W2 * H2);
    int kys[2], iys[2], nky, kxs[2], ixs[2], nkx;
    if (y & 1) {
        nky = 0;
        int iy0 = (y + 1) >> 1;
        if (iy0 < H) { kys[nky] = 0; iys[nky] = iy0; ++nky; }
        kys[nky] = 2; iys[nky] = (y - 1) >> 1; ++nky;
    } else { kys[0] = 1; iys[0] = y >> 1; nky = 1; }
    if (x & 1) {
        nkx = 0;
        int ix0 = (x + 1) >> 1;
        if (ix0 < W) { kxs[nkx] = 0; ixs[nkx] = ix0; ++nkx; }
        kxs[nkx] = 2; ixs[nkx] = (x - 1) >> 1; ++nkx;
    } else { kxs[0] = 1; ixs[0] = x >> 1; nkx = 1; }
    const int Wp = 24;
    float acc = bias[o];
    for (int ci = 0; ci < Cin; ++ci) {
        const float* ip = in + (size_t)ci * Wp * Wp;
        const float* wp = w + ((size_t)ci * Cout + o) * 9;
        for (int a = 0; a < nky; ++a)
            for (int b = 0; b < nkx; ++b)
                acc += ip[(size_t)(iys[a] + 4) * Wp + ixs[b] + 4] * wp[kys[a] * 3 + kxs[b]];
    }
    out[idx] = acc;
}

// ---------------- broadcast (1,C,H,W)*(256,1,H,W) + leaky ----------------
__global__ void bcast_mul_leaky_k(const float* __restrict__ t, const float* __restrict__ attn,
                                  float* __restrict__ out, int C, int HW) {
    size_t idx = (size_t)blockIdx.x * blockDim.x + threadIdx.x;
    size_t total = (size_t)256 * C * HW;
    if (idx >= total) return;
    int p = (int)(idx % HW);
    int c = (int)((idx / HW) % C);
    int n = (int)(idx / ((size_t)HW * C));
    out[idx] = leakyf(t[(size_t)c * HW + p] * attn[(size_t)n * HW + p]);
}

// ---------------- parity-quad fused convT (batch 256) * attn (+leaky) ----------------
template <int CIN, int COUT, bool LEAKY>
__global__ void convT_quad_k(const float* __restrict__ in, const float* __restrict__ w,
                             const float* __restrict__ bias, const float* __restrict__ attn,
                             float* __restrict__ out, int H, int W) {
    int idx = blockIdx.x * blockDim.x + threadIdx.x;
    int total = 256 * H * W;
    if (idx >= total) return;
    int ix = idx % W;
    int iy = (idx / W) % H;
    int n = idx / (W * H);
    int H2 = H << 1, W2 = W << 1;
    bool okx = (ix + 1 < W), oky = (iy + 1 < H);

    const float* p = in + ((size_t)n * CIN * H + iy) * W + ix;
    float accEE[COUT], accEO[COUT], accOE[COUT], accOO[COUT];
#pragma unroll
    for (int o = 0; o < COUT; ++o) { accEE[o] = 0.f; accEO[o] = 0.f; accOE[o] = 0.f; accOO[o] = 0.f; }

#pragma unroll 4
    for (int ci = 0; ci < CIN; ++ci) {
        float v00 = p[0];
        float v01 = okx ? p[1] : 0.f;
        float v10 = oky ? p[W] : 0.f;
        float v11 = (okx && oky) ? p[W + 1] : 0.f;
        const float* wp = w + (size_t)ci * COUT * 9;
#pragma unroll
        for (int o = 0; o < COUT; ++o) {
            const float* q = wp + o * 9;
            accEE[o] += q[4] * v00;
            accEO[o] += q[3] * v01 + q[5] * v00;
            accOE[o] += q[1] * v10 + q[7] * v00;
            accOO[o] += q[0] * v11 + q[2] * v10 + q[6] * v01 + q[8] * v00;
        }
        p += H * W;
    }

    size_t abase = ((size_t)n * H2 + 2 * iy) * W2 + 2 * ix;
    float2 aT = *(const float2*)(attn + abase);
    float2 aB = *(const float2*)(attn + abase + W2);

#pragma unroll
    for (int o = 0; o < COUT; ++o) {
        float b = bias[o];
        float rEE = (accEE[o] + b) * aT.x;
        float rEO = (accEO[o] + b) * aT.y;
        float rOE = (accOE[o] + b) * aB.x;
        float rOO = (accOO[o] + b) * aB.y;
        if (LEAKY) {
            rEE = leakyf(rEE); rEO = leakyf(rEO);
            rOE = leakyf(rOE); rOO = leakyf(rOO);
        }
        size_t ob = (((size_t)n * COUT + o) * H2 + 2 * iy) * W2 + 2 * ix;
        float2 top; top.x = rEE; top.y = rEO;
        float2 bot; bot.x = rOE; bot.y = rOO;
        *(float2*)(out + ob) = top;
        *(float2*)(out + ob + W2) = bot;
    }
}

// ---------------- valid = max over HW > 1 ----------------
__global__ void valid_k(const float* __restrict__ conf, float* __restrict__ vout) {
    int l = blockIdx.x;
    const float4* p = (const float4*)(conf + (size_t)l * 65536);
    int t = threadIdx.x;  // 1024
    float m = -3.4e38f;
    for (int i = t; i < 16384; i += 1024) {
        float4 v = p[i];
        m = fmaxf(m, fmaxf(fmaxf(v.x, v.y), fmaxf(v.z, v.w)));
    }
    __shared__ float sm[1024];
    sm[t] = m;
    __syncthreads();
    for (int o = 512; o > 0; o >>= 1) {
        if (t < o) sm[t] = fmaxf(sm[t], sm[t + o]);
        __syncthreads();
    }
    if (t == 0) vout[l] = (sm[0] > 1.f) ? 1.f : 0.f;
}

extern "C" void kernel_launch(void* const* d_in, const int* in_sizes, int n_in,
                              void* d_out, int out_size, void* d_ws, size_t ws_size,
                              hipStream_t stream) {
    const float* x1 = (const float*)d_in[0];
    const float* x2 = (const float*)d_in[1];
    const int* pts = (const int*)d_in[2];
    const float* ew[4] = {(const float*)d_in[3], (const float*)d_in[5], (const float*)d_in[7], (const float*)d_in[9]};
    const float* eb[4] = {(const float*)d_in[4], (const float*)d_in[6], (const float*)d_in[8], (const float*)d_in[10]};
    const float* dw[4] = {(const float*)d_in[11], (const float*)d_in[13], (const float*)d_in[15], (const float*)d_in[17]};
    const float* db[4] = {(const float*)d_in[12], (const float*)d_in[14], (const float*)d_in[16], (const float*)d_in[18]};

    float* ws = (float*)d_ws;
    float* h1a = ws;                    // 524288
    float* h2a = h1a + 524288;          // 524288
    float* Q   = h2a + 524288;          // 16384
    float* t0  = Q + 16384;             // 32768
    float* attn3 = t0 + 32768;          // 262144   (32x32 * 256)
    float* attn2 = attn3 + 262144;      // 1048576  (64x64 * 256)
    float* attn1 = attn2 + 1048576;     // 4194304  (128x128 * 256)
    float* attn0 = attn1 + 4194304;     // 16777216 (256x256 * 256)
    float* bufD1 = attn0 + 16777216;    // 33554432
    float* wT0 = bufD1 + 33554432;      // 216
    float* wT1 = wT0 + 216;             // 3200
    float* wT2 = wT1 + 3200;            // 25088
    float* wT3 = wT2 + 25088;           // 165888
    // pad buffers alias the FRONT of bufD1 (dead until decoder)
    float* pad0 = bufD1;                // 2*3*264*264  = 418176
    float* pad1 = pad0 + 418176;        // 2*8*136*136  = 295936
    float* pad2 = pad1 + 295936;        // 2*16*72*72   = 165888
    float* pad3 = pad2 + 165888;        // 2*32*40*40   = 102400
    float* pad4 = pad3 + 102400;        // 2*64*24*24   = 73728   (total 1056128)
    // partial buffer aliases bufD1 AFTER the pads (also dead until decoder):
    // max usage NSPLIT*2*COUT*HW = 32*2*64*1024 = 4194304 floats
    float* partialBuf = bufD1 + 1056768;   // 16B-aligned; ends at 5251072 < 33554432
    float* attnArr[4] = {attn0, attn1, attn2, attn3};

    float* conf = (float*)d_out;            // 16777216
    float* validOut = conf + 16777216;      // 256

    // zero pad borders (whole pad region) each call
    hipMemsetAsync(pad0, 0, (size_t)1056128 * 4, stream);

    // weight pre-transpose (tiny)
    wtrans_k<<<(216 + 255) / 256, 256, 0, stream>>>(ew[0], wT0, 3, 8, 9);
    wtrans_k<<<(3200 + 255) / 256, 256, 0, stream>>>(ew[1], wT1, 8, 16, 25);
    wtrans_k<<<(25088 + 255) / 256, 256, 0, stream>>>(ew[2], wT2, 16, 32, 49);
    wtrans_k<<<(165888 + 255) / 256, 256, 0, stream>>>(ew[3], wT3, 32, 64, 81);

    // stage level-0 inputs into padded layout
    pad_in_k<<<(2 * 3 * 65536) / 256, 256, 0, stream>>>(x1, x2, pad0, 3, 256, 256);

    const int Hs[4] = {256, 128, 64, 32};
    const int Couts[4] = {8, 16, 32, 64};
    float* padIn[4] = {pad0, pad1, pad2, pad3};
    float* padOut[4] = {pad1, pad2, pad3, pad4};
    const int padOutImgStride[4] = {8 * 136 * 136, 16 * 72 * 72, 32 * 40 * 40, 64 * 24 * 24};

    for (int lv = 0; lv < 4; ++lv) {
        int Hc = Hs[lv], HW = Hc * Hc;
        if (lv == 0) {
            dim3 grid(HW / 4 / 256, 2 * 1, 2);   // (64, 2, 2)
            conv_enc_tile_k<3, 8, 3, 1><<<grid, 256, 0, stream>>>(
                padIn[0], wT0, eb[0], h1a, h2a, partialBuf, Hc, Hc);
        } else if (lv == 1) {
            dim3 grid(HW / 4 / 256, 4 * 8, 2);   // (16, 32, 2) = 1024 blocks
            conv_enc_tile_k<8, 16, 5, 8><<<grid, 256, 0, stream>>>(
                padIn[1], wT1, eb[1], h1a, h2a, partialBuf, Hc, Hc);
            reduce4_k<8><<<(2 * 16 * HW / 4) / 256, 256, 0, stream>>>(
                (const float4*)partialBuf, eb[1], h1a, h2a, 16, HW);
        } else if (lv == 2) {
            dim3 grid(HW / 4 / 256, 8 * 16, 2);  // (4, 128, 2) = 1024 blocks
            conv_enc_tile_k<16, 32, 7, 16><<<grid, 256, 0, stream>>>(
                padIn[2], wT2, eb[2], h1a, h2a, partialBuf, Hc, Hc);
            reduce4_k<16><<<(2 * 32 * HW / 4) / 256, 256, 0, stream>>>(
                (const float4*)partialBuf, eb[2], h1a, h2a, 32, HW);
        } else {
            dim3 grid(HW / 4 / 256, 16 * 32, 2); // (1, 512, 2) = 1024 blocks
            conv_enc_tile_k<32, 64, 9, 32><<<grid, 256, 0, stream>>>(
                padIn[3], wT3, eb[3], h1a, h2a, partialBuf, Hc, Hc);
            reduce4_k<32><<<(2 * 64 * HW / 4) / 256, 256, 0, stream>>>(
                (const float4*)partialBuf, eb[3], h1a, h2a, 64, HW);
        }
        gatherQ_k<<<(Couts[lv] * 256 + 255) / 256, 256, 0, stream>>>(h1a, pts, Q, Couts[lv], Hc, lv);
        attn_scores_k<<<HW, 256, 0, stream>>>(h2a, Q, attnArr[lv], Couts[lv], HW);
        if (lv < 3)
            softmax_chunk_v4_k<1024><<<256, 1024, 0, stream>>>(attnArr[lv], HW);
        else
            softmax_chunk_v4_k<256><<<256, 256, 0, stream>>>(attnArr[lv], HW);
        int npool = Couts[lv] * (HW / 4);
        maxpool_pad_k<<<npool / 256, 256, 0, stream>>>(h1a, padOut[lv], Couts[lv], Hc, Hc);
        maxpool_pad_k<<<npool / 256, 256, 0, stream>>>(h2a, padOut[lv] + padOutImgStride[lv],
                                                       Couts[lv], Hc, Hc);
    }
    // pad4 img1 section now holds padded encoder output of image 2 (64,16,16)

    // decoder layer 0: convT once at batch 1, then broadcast*attn3 + leaky -> bufD1 (256,32,32,32)
    convT_b1_k<<<(32 * 32 * 32 + 255) / 256, 256, 0, stream>>>(
        pad4 + padOutImgStride[3], dw[0], db[0], t0, 64, 32, 16, 16);
    {
        size_t tot = (size_t)256 * 32 * 1024;
        bcast_mul_leaky_k<<<(unsigned)((tot + 255) / 256), 256, 0, stream>>>(t0, attn3, bufD1, 32, 1024);
    }
    // layer 1: (256,32,32,32) -> (256,16,64,64) * attn2, leaky   (staged in d_out)
    {
        int tot = 256 * 32 * 32;  // quads
        convT_quad_k<32, 16, true><<<(tot + 255) / 256, 256, 0, stream>>>(
            bufD1, dw[1], db[1], attn2, conf, 32, 32);
    }
    // layer 2: (256,16,64,64) -> (256,8,128,128) * attn1, leaky -> bufD1
    {
        int tot = 256 * 64 * 64;
        convT_quad_k<16, 8, true><<<(tot + 255) / 256, 256, 0, stream>>>(
            conf, dw[2], db[2], attn1, bufD1, 64, 64);
    }
    // layer 3: (256,8,128,128) -> (256,1,256,256) * attn0, no leaky -> conf
    {
        int tot = 256 * 128 * 128;
        convT_quad_k<8, 1, false><<<(tot + 255) / 256, 256, 0, stream>>>(
            bufD1, dw[3], db[3], attn0, conf, 128, 128);
    }
    valid_k<<<256, 1024, 0, stream>>>(conf, validOut);
}